// Round 10
// baseline (424.766 us; speedup 1.0000x reference)
//
#include <hip/hip_runtime.h>
#include <hip/hip_bf16.h>
#include <math.h>

#define G_GRAPHS 256
#define EPG 2048
#define E_TOT 524288
#define HF 256
#define FIN 128

// ---------------------------------------------------------------------------
// GEMM model (R8/R9-validated): time >= LDS-pipe cycles; ratio LDS/FMA =
// 6*(RM+CN)/(RM*CN). v8 (4x8) = 2.25 -> 61.5us measured. v12 (8x8, BK=16)
// = 1.5 -> 41us bound; s0 (4 blk/CU) hit ~43, s1 (2 blk/CU, grid-limited)
// stalled at 62.6 from 32 barrier-drains. v13 = v12 + dbuf (34KB, still
// 4 blk/CU ceiling): one barrier per tile. W must be staged (v5/v10 lesson).
// ---------------------------------------------------------------------------

// v8: 64x128 tile, 4x8/thread, BK=32 (R5-proven; used for s2 where a
// 128-row tile would give 1 block/CU).
template <int K>
__global__ __launch_bounds__(256, 4)
void gemm_v8(const float* __restrict__ A, const float* __restrict__ W,
             float* __restrict__ C) {
    __shared__ __align__(16) float As[32 * 68];
    __shared__ __align__(16) float Wa[32 * 68];
    __shared__ __align__(16) float Wb[32 * 68];
    const int tid = threadIdx.x;
    const int tx = tid & 15;
    const int ty = tid >> 4;
    const int r0 = blockIdx.x * 64;
    const int c0 = blockIdx.y * 128;
    const int l8 = tid >> 3;
    const int kq = tid & 7;
    const int wkk = tid >> 5;
    const int wc = tid & 31;
    float acc[4][8] = {{0.f}};
    float4 va0, va1, vw0, vw1, vw2, vw3;

    auto load_regs = [&](int k0) {
        va0 = *(const float4*)&A[(size_t)(r0 + l8) * K + k0 + 4 * kq];
        va1 = *(const float4*)&A[(size_t)(r0 + 32 + l8) * K + k0 + 4 * kq];
        vw0 = *(const float4*)&W[(size_t)(k0 + 0  + wkk) * 256 + c0 + 4 * wc];
        vw1 = *(const float4*)&W[(size_t)(k0 + 8  + wkk) * 256 + c0 + 4 * wc];
        vw2 = *(const float4*)&W[(size_t)(k0 + 16 + wkk) * 256 + c0 + 4 * wc];
        vw3 = *(const float4*)&W[(size_t)(k0 + 24 + wkk) * 256 + c0 + 4 * wc];
    };
    auto write_stage = [&]() {
        {
            int rs = l8 ^ (kq << 3);
            As[(4 * kq + 0) * 68 + rs] = va0.x;
            As[(4 * kq + 1) * 68 + rs] = va0.y;
            As[(4 * kq + 2) * 68 + rs] = va0.z;
            As[(4 * kq + 3) * 68 + rs] = va0.w;
        }
        {
            int rs = (32 + l8) ^ (kq << 3);
            As[(4 * kq + 0) * 68 + rs] = va1.x;
            As[(4 * kq + 1) * 68 + rs] = va1.y;
            As[(4 * kq + 2) * 68 + rs] = va1.z;
            As[(4 * kq + 3) * 68 + rs] = va1.w;
        }
        if (wc < 16) {
            *(float4*)&Wa[(0  + wkk) * 68 + 4 * wc] = vw0;
            *(float4*)&Wa[(8  + wkk) * 68 + 4 * wc] = vw1;
            *(float4*)&Wa[(16 + wkk) * 68 + 4 * wc] = vw2;
            *(float4*)&Wa[(24 + wkk) * 68 + 4 * wc] = vw3;
        } else {
            *(float4*)&Wb[(0  + wkk) * 68 + 4 * (wc - 16)] = vw0;
            *(float4*)&Wb[(8  + wkk) * 68 + 4 * (wc - 16)] = vw1;
            *(float4*)&Wb[(16 + wkk) * 68 + 4 * (wc - 16)] = vw2;
            *(float4*)&Wb[(24 + wkk) * 68 + 4 * (wc - 16)] = vw3;
        }
    };
    auto compute = [&]() {
#pragma unroll 4
        for (int kk = 0; kk < 32; ++kk) {
            const int g = (ty * 4) ^ ((kk >> 2) << 3);
            const float4 a0 = *(const float4*)&As[kk * 68 + g];
            const float4 w0 = *(const float4*)&Wa[kk * 68 + tx * 4];
            const float4 w1 = *(const float4*)&Wb[kk * 68 + tx * 4];
            float av[4] = {a0.x, a0.y, a0.z, a0.w};
            float wv_[8] = {w0.x, w0.y, w0.z, w0.w, w1.x, w1.y, w1.z, w1.w};
#pragma unroll
            for (int i = 0; i < 4; ++i)
#pragma unroll
                for (int j = 0; j < 8; ++j)
                    acc[i][j] += av[i] * wv_[j];
        }
    };

    load_regs(0);
    write_stage();
    __syncthreads();
    for (int k0 = 0; k0 < K - 32; k0 += 32) {
        load_regs(k0 + 32);
        compute();
        __syncthreads();
        write_stage();
        __syncthreads();
    }
    compute();

#pragma unroll
    for (int i = 0; i < 4; ++i) {
        float4 v0 = make_float4(acc[i][0], acc[i][1], acc[i][2], acc[i][3]);
        float4 v1 = make_float4(acc[i][4], acc[i][5], acc[i][6], acc[i][7]);
        size_t base = (size_t)(r0 + ty * 4 + i) * 256 + c0 + tx * 4;
        *(float4*)&C[base] = v0;
        *(float4*)&C[base + 64] = v1;
    }
}

// ---------------------------------------------------------------------------
// v13: v12 (128x128, 8x8/thread, BK=16, 0-conflict layouts) + DOUBLE BUFFER.
// One barrier per K-tile (R9: v12's 2-barrier/tile cost s1 ~21us at 2 blk/CU).
// LDS 34KB -> still 4 blocks/CU ceiling (unlike v9's 52KB -> 3).
// ---------------------------------------------------------------------------
template <int K>
__global__ __launch_bounds__(256, 4)
void gemm_v13(const float* __restrict__ A, const float* __restrict__ W,
              float* __restrict__ C) {
    __shared__ __align__(16) float As[2][16 * 132];
    __shared__ __align__(16) float Wa[2][16 * 68];
    __shared__ __align__(16) float Wb[2][16 * 68];
    const int tid = threadIdx.x;
    const int tx = tid & 15;     // col groups: c0 + tx*4, c0 + 64 + tx*4
    const int ty = tid >> 4;     // rows r0 + ty*8 .. +7
    const int r0 = blockIdx.x * 128;
    const int c0 = blockIdx.y * 128;
    const int sr = tid >> 1;     // A staging row 0..127
    const int sq = tid & 1;      // A staging quad base: quads sq and sq+2
    const int wkk = tid >> 5;    // W staging kk 0..7 (and +8)
    const int wc = tid & 31;     // W staging float4 col index
    float acc[8][8] = {{0.f}};
    float4 va0, va1, vw0, vw1;

    auto load_regs = [&](int k0) {
        va0 = *(const float4*)&A[(size_t)(r0 + sr) * K + k0 + 4 * sq];
        va1 = *(const float4*)&A[(size_t)(r0 + sr) * K + k0 + 8 + 4 * sq];
        vw0 = *(const float4*)&W[(size_t)(k0 + wkk) * 256 + c0 + 4 * wc];
        vw1 = *(const float4*)&W[(size_t)(k0 + 8 + wkk) * 256 + c0 + 4 * wc];
    };
    auto write_stage = [&](int b) {
        {   // quad sq: 2-way max on banks (free)
            int rs = sr ^ (sq << 3);
            As[b][(4 * sq + 0) * 132 + rs] = va0.x;
            As[b][(4 * sq + 1) * 132 + rs] = va0.y;
            As[b][(4 * sq + 2) * 132 + rs] = va0.z;
            As[b][(4 * sq + 3) * 132 + rs] = va0.w;
        }
        {   // quad sq+2
            int kq = sq + 2;
            int rs = sr ^ (kq << 3);
            As[b][(4 * kq + 0) * 132 + rs] = va1.x;
            As[b][(4 * kq + 1) * 132 + rs] = va1.y;
            As[b][(4 * kq + 2) * 132 + rs] = va1.z;
            As[b][(4 * kq + 3) * 132 + rs] = va1.w;
        }
        if (wc < 16) {
            *(float4*)&Wa[b][wkk * 68 + 4 * wc] = vw0;
            *(float4*)&Wa[b][(8 + wkk) * 68 + 4 * wc] = vw1;
        } else {
            *(float4*)&Wb[b][wkk * 68 + 4 * (wc - 16)] = vw0;
            *(float4*)&Wb[b][(8 + wkk) * 68 + 4 * (wc - 16)] = vw1;
        }
    };
    auto compute = [&](int b) {
#pragma unroll 4
        for (int kk = 0; kk < 16; ++kk) {
            const int g = (ty ^ (kk >> 2)) << 3;   // row-block XOR unswizzle
            const float4 a0 = *(const float4*)&As[b][kk * 132 + g];
            const float4 a1 = *(const float4*)&As[b][kk * 132 + g + 4];
            const float4 w0 = *(const float4*)&Wa[b][kk * 68 + tx * 4];
            const float4 w1 = *(const float4*)&Wb[b][kk * 68 + tx * 4];
            float av[8] = {a0.x, a0.y, a0.z, a0.w, a1.x, a1.y, a1.z, a1.w};
            float wv_[8] = {w0.x, w0.y, w0.z, w0.w, w1.x, w1.y, w1.z, w1.w};
#pragma unroll
            for (int i = 0; i < 8; ++i)
#pragma unroll
                for (int j = 0; j < 8; ++j)
                    acc[i][j] += av[i] * wv_[j];
        }
    };

    load_regs(0);
    write_stage(0);
    __syncthreads();
    int cur = 0;
    for (int k0 = 0; k0 < K - 16; k0 += 16) {
        load_regs(k0 + 16);    // issue early: in flight under compute
        compute(cur);
        write_stage(cur ^ 1);  // other buffer: no read/write hazard
        __syncthreads();       // publish next buffer (ONE barrier per tile)
        cur ^= 1;
    }
    compute(cur);

#pragma unroll
    for (int i = 0; i < 8; ++i) {
        float4 v0 = make_float4(acc[i][0], acc[i][1], acc[i][2], acc[i][3]);
        float4 v1 = make_float4(acc[i][4], acc[i][5], acc[i][6], acc[i][7]);
        size_t base = (size_t)(r0 + ty * 8 + i) * 256 + c0 + tx * 4;
        *(float4*)&C[base] = v0;
        *(float4*)&C[base + 64] = v1;
    }
}

// ---------------------------------------------------------------------------
// CSR body (parallel stable counting sort, packed (src, dinv_src) slots).
// ---------------------------------------------------------------------------
template <bool IDENT>
__device__ __forceinline__ void csr_body(
    const int* __restrict__ ei, int g, int t, int npg, const int* curL,
    int* __restrict__ degS, float* __restrict__ dinvS,
    int* __restrict__ startsS, int2* __restrict__ slots2,
    int* cul, short* dstv, unsigned char* rnk, int (*h)[256],
    int* cnt, int* st) {
    const int lane = t & 63;
    const int wv = t >> 6;
    for (int i = t; i < 32 * 256; i += 256) ((int*)h)[i] = 0;
    for (int e = t; e < EPG; e += 256) {
        size_t idx = (size_t)g * EPG + e;
        int u = ei[idx] - g * 256;
        int v = ei[E_TOT + idx] - g * 256;
        int cu = IDENT ? u : curL[u];
        int cv = IDENT ? v : curL[v];
        bool valid = (cu >= 0 && cv >= 0);
        cul[e] = cu;
        dstv[e] = valid ? (short)cv : (short)256;
    }
    __syncthreads();
    for (int c = wv; c < 32; c += 4) {
        int e = c * 64 + lane;
        int d = (int)dstv[e];
        unsigned long long m = ~0ULL;
#pragma unroll
        for (int b = 0; b < 9; ++b) {
            unsigned long long bb = __ballot((d >> b) & 1);
            m &= ((d >> b) & 1) ? bb : ~bb;
        }
        int r = __popcll(m & ((1ULL << lane) - 1ULL));
        rnk[e] = (unsigned char)r;
        if (r == 0 && d < 256) h[c][d] = __popcll(m);
    }
    __syncthreads();
    if (t < npg) {
        int run = 0;
        for (int c = 0; c < 32; ++c) { int v = h[c][t]; h[c][t] = run; run += v; }
        cnt[t] = run;
        degS[g * npg + t] = run + 1;
        dinvS[g * npg + t] = 1.0f / sqrtf((float)(run + 1));
    }
    __syncthreads();
    if (t == 0) {
        int run = 0;
        for (int i = 0; i < npg; ++i) { st[i] = run; run += cnt[i]; }
    }
    __syncthreads();
    if (t < npg) startsS[g * npg + t] = g * EPG + st[t];
    for (int e = t; e < EPG; e += 256) {
        int d = (int)dstv[e];
        if (d < npg) {
            int slot = st[d] + h[e >> 6][d] + (int)rnk[e];
            int cu = cul[e];
            float dv = 1.0f / sqrtf((float)(cnt[cu] + 1));   // == dinvS[src]
            slots2[g * EPG + slot] = make_int2(g * npg + cu, __float_as_int(dv));
        }
    }
}

// ---------------------------------------------------------------------------
__global__ __launch_bounds__(256)
void fused_init_csr(const int* __restrict__ ei, int* __restrict__ cur,
                    int* __restrict__ degS, float* __restrict__ dinvS,
                    int* __restrict__ startsS, int2* __restrict__ slots2) {
    __shared__ int cul[EPG];
    __shared__ short dstv[EPG];
    __shared__ unsigned char rnk[EPG];
    __shared__ int h[32][256];
    __shared__ int cnt[256];
    __shared__ int st[256];
    const int g = blockIdx.x;
    const int t = threadIdx.x;
    cur[g * 256 + t] = t;
    csr_body<true>(ei, g, t, 256, nullptr, degS, dinvS, startsS, slots2,
                   cul, dstv, rnk, h, cnt, st);
}

// ---------------------------------------------------------------------------
// conv + relu + pool score (R2-proven wave-per-node, float4 per lane).
// ---------------------------------------------------------------------------
__global__ __launch_bounds__(256)
void agg_score2(const int* __restrict__ degS, const float* __restrict__ dinvS,
                const int* __restrict__ startsS, const int2* __restrict__ slots2,
                const float* __restrict__ HL, float* __restrict__ H2,
                const float* __restrict__ bias, const float* __restrict__ pw,
                float* __restrict__ score, int nbOver8) {
    __shared__ float vrow[4][256];
    const int t = threadIdx.x;
    const int wv = t >> 6;
    const int lane = t & 63;
    const int blk = (blockIdx.x & 7) * nbOver8 + (blockIdx.x >> 3);
    const int node = blk * 4 + wv;
    const int cntE = degS[node] - 1;
    const float degF = (float)(cntE + 1);
    const float dn = dinvS[node];
    const int2* sl = slots2 + startsS[node];
    float ax = 0.f, ay = 0.f, az = 0.f, aw = 0.f;
    int j = 0;
    for (; j + 8 <= cntE; j += 8) {
        int2 s[8];
#pragma unroll
        for (int u = 0; u < 8; ++u) s[u] = sl[j + u];
        float4 hv[8];
#pragma unroll
        for (int u = 0; u < 8; ++u)
            hv[u] = *(const float4*)&HL[(size_t)s[u].x * 256 + 4 * lane];
#pragma unroll
        for (int u = 0; u < 8; ++u) {
            float dv = __int_as_float(s[u].y);
            ax += dv * hv[u].x; ay += dv * hv[u].y;
            az += dv * hv[u].z; aw += dv * hv[u].w;
        }
    }
    for (; j + 4 <= cntE; j += 4) {
        int2 s[4];
#pragma unroll
        for (int u = 0; u < 4; ++u) s[u] = sl[j + u];
        float4 hv[4];
#pragma unroll
        for (int u = 0; u < 4; ++u)
            hv[u] = *(const float4*)&HL[(size_t)s[u].x * 256 + 4 * lane];
#pragma unroll
        for (int u = 0; u < 4; ++u) {
            float dv = __int_as_float(s[u].y);
            ax += dv * hv[u].x; ay += dv * hv[u].y;
            az += dv * hv[u].z; aw += dv * hv[u].w;
        }
    }
    for (; j < cntE; ++j) {
        int2 sv = sl[j];
        float dv = __int_as_float(sv.y);
        float4 hv = *(const float4*)&HL[(size_t)sv.x * 256 + 4 * lane];
        ax += dv * hv.x; ay += dv * hv.y; az += dv * hv.z; aw += dv * hv.w;
    }
    const float4 hn = *(const float4*)&HL[(size_t)node * 256 + 4 * lane];
    const float4 bi = *(const float4*)&bias[4 * lane];
    float4 v;
    v.x = ax * dn + hn.x / degF + bi.x;  v.x = fmaxf(v.x, 0.f);
    v.y = ay * dn + hn.y / degF + bi.y;  v.y = fmaxf(v.y, 0.f);
    v.z = az * dn + hn.z / degF + bi.z;  v.z = fmaxf(v.z, 0.f);
    v.w = aw * dn + hn.w / degF + bi.w;  v.w = fmaxf(v.w, 0.f);
    *(float4*)&H2[(size_t)node * 256 + 4 * lane] = v;
    *(float4*)&vrow[wv][4 * lane] = v;
    float pr = 0.f, s2p = 0.f;
    for (int jj = 0; jj < 4; ++jj) {
        int f = lane + 64 * jj;
        float w = pw[f];
        pr += vrow[wv][f] * w;
        s2p += w * w;
    }
    for (int off = 32; off; off >>= 1) {
        pr += __shfl_down(pr, off, 64);
        s2p += __shfl_down(s2p, off, 64);
    }
    s2p = __shfl(s2p, 0, 64);
    if (lane == 0) score[node] = tanhf(pr / sqrtf(s2p));
}

// ---------------------------------------------------------------------------
// topk(s) + cur update + pool + readout + CSR(s+1), fused (R8-proven).
// ---------------------------------------------------------------------------
__global__ __launch_bounds__(256)
void fused_topk_csr(const float* __restrict__ score, int npg, int k,
                    const float* __restrict__ H2, float* __restrict__ OUT,
                    float* __restrict__ outacc, int* __restrict__ cur, int first,
                    const int* __restrict__ ei,
                    int* __restrict__ degS, float* __restrict__ dinvS,
                    int* __restrict__ startsS, int2* __restrict__ slots2) {
    __shared__ float ss[256];
    __shared__ int si_[256];
    __shared__ int rankOf[256];
    __shared__ int curL[256];
    __shared__ int cul[EPG];
    __shared__ short dstv[EPG];
    __shared__ unsigned char rnk[EPG];
    __shared__ int h[32][256];
    __shared__ int cnt[256];
    __shared__ int st[256];
    const int g = blockIdx.x;
    const int t = threadIdx.x;
    if (t < npg) { ss[t] = score[g * npg + t]; si_[t] = t; }
    else         { ss[t] = -INFINITY; si_[t] = 0x7FFFFFFF; }
    for (int size = 2; size <= 256; size <<= 1) {
        for (int stride = size >> 1; stride > 0; stride >>= 1) {
            __syncthreads();
            int i = t, j = t ^ stride;
            if (j > i) {
                float a = ss[i], b = ss[j];
                int ia = si_[i], ib = si_[j];
                bool inOrder = (a > b) || (a == b && ia < ib);
                bool desc = ((i & size) == 0);
                if (desc ? !inOrder : inOrder) {
                    ss[i] = b; ss[j] = a; si_[i] = ib; si_[j] = ia;
                }
            }
        }
    }
    __syncthreads();
    rankOf[t] = -1;
    __syncthreads();
    if (t < k) rankOf[si_[t]] = t;
    __syncthreads();
    {
        int v = g * 256 + t;
        int c = cur[v];
        int nc = (c >= 0) ? rankOf[c] : -1;
        cur[v] = nc;
        curL[t] = nc;
    }
    const size_t gb = (size_t)g * npg * 256;
    float mx = -INFINITY, sm = 0.f;
    for (int n = 0; n < k; n += 4) {
        float v0 = H2[gb + (size_t)si_[n + 0] * 256 + t] * ss[n + 0];
        float v1 = H2[gb + (size_t)si_[n + 1] * 256 + t] * ss[n + 1];
        float v2 = H2[gb + (size_t)si_[n + 2] * 256 + t] * ss[n + 2];
        float v3 = H2[gb + (size_t)si_[n + 3] * 256 + t] * ss[n + 3];
        size_t ob = ((size_t)g * k + n) * 256 + t;
        OUT[ob]       = v0;
        OUT[ob + 256] = v1;
        OUT[ob + 512] = v2;
        OUT[ob + 768] = v3;
        mx = fmaxf(mx, v0); sm += v0;
        mx = fmaxf(mx, v1); sm += v1;
        mx = fmaxf(mx, v2); sm += v2;
        mx = fmaxf(mx, v3); sm += v3;
    }
    float mean = sm / (float)k;
    if (first) {
        outacc[g * 512 + t] = mx;
        outacc[g * 512 + 256 + t] = mean;
    } else {
        outacc[g * 512 + t] += mx;
        outacc[g * 512 + 256 + t] += mean;
    }
    __syncthreads();
    csr_body<false>(ei, g, t, k, curL, degS, dinvS, startsS, slots2,
                    cul, dstv, rnk, h, cnt, st);
}

// ---------------------------------------------------------------------------
// topk(2) + readout + MLP head, fused (R8-proven).
// ---------------------------------------------------------------------------
__global__ __launch_bounds__(256)
void fused_topk_mlp(const float* __restrict__ score, int npg, int k,
                    const float* __restrict__ H2,
                    const float* __restrict__ outacc,
                    const float* __restrict__ l1w, const float* __restrict__ l1b,
                    const float* __restrict__ l2w, const float* __restrict__ l2b,
                    const float* __restrict__ l3w, const float* __restrict__ l3b,
                    float* __restrict__ out) {
    __shared__ float ss[256];
    __shared__ int si_[256];
    __shared__ float row[512];
    __shared__ float h1[256];
    __shared__ float h2[128];
    const int g = blockIdx.x;
    const int t = threadIdx.x;
    if (t < npg) { ss[t] = score[g * npg + t]; si_[t] = t; }
    else         { ss[t] = -INFINITY; si_[t] = 0x7FFFFFFF; }
    for (int size = 2; size <= 256; size <<= 1) {
        for (int stride = size >> 1; stride > 0; stride >>= 1) {
            __syncthreads();
            int i = t, j = t ^ stride;
            if (j > i) {
                float a = ss[i], b = ss[j];
                int ia = si_[i], ib = si_[j];
                bool inOrder = (a > b) || (a == b && ia < ib);
                bool desc = ((i & size) == 0);
                if (desc ? !inOrder : inOrder) {
                    ss[i] = b; ss[j] = a; si_[i] = ib; si_[j] = ia;
                }
            }
        }
    }
    __syncthreads();
    const size_t gb = (size_t)g * npg * 256;
    float mx = -INFINITY, sm = 0.f;
    for (int n = 0; n < k; n += 4) {
        float v0 = H2[gb + (size_t)si_[n + 0] * 256 + t] * ss[n + 0];
        float v1 = H2[gb + (size_t)si_[n + 1] * 256 + t] * ss[n + 1];
        float v2 = H2[gb + (size_t)si_[n + 2] * 256 + t] * ss[n + 2];
        float v3 = H2[gb + (size_t)si_[n + 3] * 256 + t] * ss[n + 3];
        mx = fmaxf(mx, v0); sm += v0;
        mx = fmaxf(mx, v1); sm += v1;
        mx = fmaxf(mx, v2); sm += v2;
        mx = fmaxf(mx, v3); sm += v3;
    }
    float mean = sm / (float)k;
    row[t]       = outacc[g * 512 + t] + mx;
    row[256 + t] = outacc[g * 512 + 256 + t] + mean;
    __syncthreads();
    {
        float a = l1b[t];
        for (int j = 0; j < 512; ++j) a += row[j] * l1w[j * 256 + t];
        h1[t] = fmaxf(a, 0.f);
    }
    __syncthreads();
    if (t < 128) {
        float a2 = l2b[t];
        for (int j = 0; j < 256; ++j) a2 += h1[j] * l2w[j * 128 + t];
        h2[t] = fmaxf(a2, 0.f);
    }
    __syncthreads();
    if (t == 0) {
        float l0 = l3b[0], l1 = l3b[1];
        for (int j = 0; j < 128; ++j) {
            float h = h2[j];
            l0 += h * l3w[j * 2 + 0];
            l1 += h * l3w[j * 2 + 1];
        }
        float m = fmaxf(l0, l1);
        float lse = m + logf(expf(l0 - m) + expf(l1 - m));
        out[g * 2 + 0] = l0 - lse;
        out[g * 2 + 1] = l1 - lse;
    }
}

// ============================================================================
// Fallback: proven R15 monolith (used only if ws_size is too small)
// ============================================================================
__global__ __launch_bounds__(256, 1)
void gnn_mono(const float* __restrict__ x, const int* __restrict__ ei,
              const float* __restrict__ gw0, const float* __restrict__ gb0,
              const float* __restrict__ gw1, const float* __restrict__ gb1,
              const float* __restrict__ gw2, const float* __restrict__ gb2,
              const float* __restrict__ pw0, const float* __restrict__ pw1,
              const float* __restrict__ pw2,
              const float* __restrict__ l1w, const float* __restrict__ l1b,
              const float* __restrict__ l2w, const float* __restrict__ l2b,
              const float* __restrict__ l3w, const float* __restrict__ l3b,
              float* __restrict__ out, float* __restrict__ ws) {
    const int g = blockIdx.x;
    const int t = threadIdx.x;
    float* P = ws + (size_t)g * HF * 256;
    float* Q = ws + (size_t)G_GRAPHS * HF * 256 + (size_t)g * HF * 256;
    __shared__ int   eb[EPG];
    __shared__ int   slots[EPG];
    __shared__ int   curID[256];
    __shared__ int   cntL[256];
    __shared__ int   startL[256];
    __shared__ float degF[256];
    __shared__ float dinv[256];
    __shared__ float sa[256];
    __shared__ float ss[256];
    __shared__ int   si_[256];
    __shared__ float scoreV[256];
    __shared__ int   kept[128];
    __shared__ int   rankOf[256];
    __shared__ float row[512];
    for (int e = t; e < EPG; e += 256) {
        size_t idx = (size_t)g * EPG + e;
        eb[e] = ((ei[idx] - g * 256) << 8) | (ei[E_TOT + idx] - g * 256);
    }
    curID[t] = t;
    float accMx = 0.f, accMn = 0.f;
    const float* GW[3] = {gw0, gw1, gw2};
    const float* GB[3] = {gb0, gb1, gb2};
    const float* PW[3] = {pw0, pw1, pw2};
    const int kk[3] = {128, 64, 32};
    int npg = 256;
    __syncthreads();
    for (int s = 0; s < 3; ++s) {
        const int knext = kk[s];
        {
            const float* Wp = GW[s];
            const int K = (s == 0) ? FIN : HF;
            for (int n = 0; n < npg; ++n) {
                if (s == 0) { if (t < FIN) sa[t] = x[(size_t)(g * 256 + n) * FIN + t]; }
                else sa[t] = P[(size_t)n * HF + t];
                __syncthreads();
                float a = 0.f;
                for (int k2 = 0; k2 < K; ++k2) a += sa[k2] * Wp[k2 * HF + t];
                Q[(size_t)n * HF + t] = a;
                __syncthreads();
            }
        }
        cntL[t] = 0;
        __syncthreads();
        for (int e = t; e < EPG; e += 256) {
            int p = eb[e];
            int cu = curID[p >> 8], cv = curID[p & 255];
            if (cu >= 0 && cv >= 0) atomicAdd(&cntL[cv], 1);
        }
        __syncthreads();
        if (t == 0) { int run = 0; for (int i = 0; i < npg; ++i) { startL[i] = run; run += cntL[i]; } }
        __syncthreads();
        if (t < npg) {
            float d = (float)cntL[t] + 1.0f;
            degF[t] = d;
            dinv[t] = 1.0f / sqrtf(d);
            int c = startL[t];
            for (int e = 0; e < EPG; ++e) {
                int p = eb[e];
                int cu = curID[p >> 8], cv = curID[p & 255];
                if (cu >= 0 && cv >= 0 && cv == t) slots[c++] = e;
            }
        }
        __syncthreads();
        {
            const float bb = GB[s][t];
            for (int n = 0; n < npg; ++n) {
                float acc = 0.f;
                const int s0 = startL[n], s1 = s0 + cntL[n];
                for (int j = s0; j < s1; ++j) {
                    int scur = curID[eb[slots[j]] >> 8];
                    acc += dinv[scur] * Q[(size_t)scur * HF + t];
                }
                float v = acc * dinv[n] + Q[(size_t)n * HF + t] / degF[n] + bb;
                P[(size_t)n * HF + t] = fmaxf(v, 0.f);
            }
        }
        __syncthreads();
        {
            const float* pwp = PW[s];
            const int lane = t & 63, wv = t >> 6;
            float s2p = 0.f;
            for (int j = 0; j < 4; ++j) { float w = pwp[lane + 64 * j]; s2p += w * w; }
            for (int off = 32; off; off >>= 1) s2p += __shfl_down(s2p, off, 64);
            s2p = __shfl(s2p, 0, 64);
            const float nw = sqrtf(s2p);
            for (int n = wv; n < npg; n += 4) {
                float pr = 0.f;
                for (int j = 0; j < 4; ++j) { int f = lane + 64 * j; pr += P[(size_t)n * HF + f] * pwp[f]; }
                for (int off = 32; off; off >>= 1) pr += __shfl_down(pr, off, 64);
                if (lane == 0) scoreV[n] = tanhf(pr / nw);
            }
        }
        __syncthreads();
        if (t < npg) { ss[t] = scoreV[t]; si_[t] = t; }
        else         { ss[t] = -INFINITY; si_[t] = 0x7FFFFFFF; }
        for (int size = 2; size <= 256; size <<= 1) {
            for (int stride = size >> 1; stride > 0; stride >>= 1) {
                __syncthreads();
                int i = t, j = t ^ stride;
                if (j > i) {
                    float a = ss[i], b = ss[j];
                    int ia = si_[i], ib = si_[j];
                    bool inOrder = (a > b) || (a == b && ia < ib);
                    bool desc = ((i & size) == 0);
                    if (desc ? !inOrder : inOrder) { ss[i] = b; ss[j] = a; si_[i] = ib; si_[j] = ia; }
                }
            }
        }
        __syncthreads();
        if (t < knext) kept[t] = si_[t];
        __syncthreads();
        {
            float mx = -INFINITY, sm = 0.f;
            for (int n = 0; n < knext; ++n) {
                int o = kept[n];
                float vv = P[(size_t)o * HF + t] * scoreV[o];
                Q[(size_t)n * HF + t] = vv;
                mx = fmaxf(mx, vv);
                sm += vv;
            }
            accMx += mx;
            accMn += sm / (float)knext;
        }
        rankOf[t] = -1;
        __syncthreads();
        if (t < knext) rankOf[kept[t]] = t;
        __syncthreads();
        { int c = curID[t]; curID[t] = (c >= 0) ? rankOf[c] : -1; }
        __syncthreads();
        { float* tmp = P; P = Q; Q = tmp; }
        npg = knext;
    }
    row[t] = accMx;
    row[256 + t] = accMn;
    __syncthreads();
    { float a = l1b[t]; for (int j = 0; j < 512; ++j) a += row[j] * l1w[j * 256 + t]; scoreV[t] = fmaxf(a, 0.f); }
    __syncthreads();
    if (t < 128) { float a2 = l2b[t]; for (int j = 0; j < 256; ++j) a2 += scoreV[j] * l2w[j * 128 + t]; sa[t] = fmaxf(a2, 0.f); }
    __syncthreads();
    if (t == 0) {
        float l0 = l3b[0], l1 = l3b[1];
        for (int j = 0; j < 128; ++j) { float h = sa[j]; l0 += h * l3w[j * 2 + 0]; l1 += h * l3w[j * 2 + 1]; }
        float m = fmaxf(l0, l1);
        float lse = m + logf(expf(l0 - m) + expf(l1 - m));
        out[g * 2 + 0] = l0 - lse;
        out[g * 2 + 1] = l1 - lse;
    }
}

// ============================================================================
extern "C" void kernel_launch(void* const* d_in, const int* in_sizes, int n_in,
                              void* d_out, int out_size, void* d_ws, size_t ws_size,
                              hipStream_t stream) {
    const float* x   = (const float*)d_in[0];
    const int*   ei  = (const int*)d_in[1];
    const float* gw0 = (const float*)d_in[3];
    const float* gb0 = (const float*)d_in[4];
    const float* gw1 = (const float*)d_in[5];
    const float* gb1 = (const float*)d_in[6];
    const float* gw2 = (const float*)d_in[7];
    const float* gb2 = (const float*)d_in[8];
    const float* pw0 = (const float*)d_in[9];
    const float* pw1 = (const float*)d_in[10];
    const float* pw2 = (const float*)d_in[11];
    const float* l1w = (const float*)d_in[12];
    const float* l1b = (const float*)d_in[13];
    const float* l2w = (const float*)d_in[14];
    const float* l2b = (const float*)d_in[15];
    const float* l3w = (const float*)d_in[16];
    const float* l3b = (const float*)d_in[17];
    float* out = (float*)d_out;

    const size_t SLAB = (size_t)65536 * 256;
    char* p = (char*)d_ws;
    float* P      = (float*)p; p += SLAB * 4;
    float* Q      = (float*)p; p += SLAB * 4;
    int*   cur    = (int*)p;   p += (size_t)65536 * 4;
    int*   degS   = (int*)p;   p += (size_t)65536 * 4;
    float* dinvS  = (float*)p; p += (size_t)65536 * 4;
    int*   starts = (int*)p;   p += (size_t)65536 * 4;
    int2*  slots2 = (int2*)p;  p += (size_t)E_TOT * 8;
    float* score  = (float*)p; p += (size_t)65536 * 4;
    int*   kept   = (int*)p;   p += (size_t)32768 * 4;
    float* outacc = (float*)p; p += (size_t)G_GRAPHS * 512 * 4;
    const size_t needed = (size_t)(p - (char*)d_ws);

    if (ws_size < needed) {
        gnn_mono<<<G_GRAPHS, 256, 0, stream>>>(
            x, ei, gw0, gb0, gw1, gb1, gw2, gb2, pw0, pw1, pw2,
            l1w, l1b, l2w, l2b, l3w, l3b, out, (float*)d_ws);
        return;
    }

    const int   npg[3] = {256, 128, 64};
    const int   kk[3]  = {128, 64, 32};
    const int   Ns[3]  = {65536, 32768, 16384};
    const float* GW[3] = {gw0, gw1, gw2};
    const float* GB[3] = {gb0, gb1, gb2};
    const float* PW[3] = {pw0, pw1, pw2};

    float* HLs[3]   = {P, Q, P};
    float* H2s[3]   = {Q, P, Q};
    float* POOLs[3] = {P, Q, P};

    // init cur + CSR(0), fused
    fused_init_csr<<<G_GRAPHS, 256, 0, stream>>>(ei, cur, degS, dinvS,
                                                 starts, slots2);

    for (int s = 0; s < 3; ++s) {
        const int n = Ns[s];
        const int k = kk[s];
        // 1) GEMM: v13 (8x8, dbuf, 1 barrier/tile) for s0/s1; v8 for s2
        if (s == 0) {
            gemm_v13<FIN><<<dim3(n / 128, 2), 256, 0, stream>>>(x, GW[s], HLs[s]);
        } else if (s == 1) {
            gemm_v13<HF><<<dim3(n / 128, 2), 256, 0, stream>>>(POOLs[s - 1], GW[s], HLs[s]);
        } else {
            gemm_v8<HF><<<dim3(n / 64, 2), 256, 0, stream>>>(POOLs[s - 1], GW[s], HLs[s]);
        }
        // 2) conv + score (wave-per-node, float4 gathers)
        agg_score2<<<n / 4, 256, 0, stream>>>(degS, dinvS, starts, slots2,
                                              HLs[s], H2s[s], GB[s], PW[s], score,
                                              n / 32);
        // 3) topk + pool + readout (+ CSR of next stage, or MLP at the end)
        if (s < 2) {
            fused_topk_csr<<<G_GRAPHS, 256, 0, stream>>>(
                score, npg[s], k, H2s[s], POOLs[s], outacc, cur, s == 0 ? 1 : 0,
                ei, degS, dinvS, starts, slots2);
        } else {
            fused_topk_mlp<<<G_GRAPHS, 256, 0, stream>>>(
                score, npg[s], k, H2s[s], outacc,
                l1w, l1b, l2w, l2b, l3w, l3b, out);
        }
    }
}